// Round 4
// baseline (721.223 us; speedup 1.0000x reference)
//
#include <hip/hip_runtime.h>
#include <float.h>

#define DIMC 512
#define WW 64
#define RR 128
#define NH 8
#define HDIM 64
#define NSEQ 65      // 1+W
#define MSEQ 129     // 1+R

typedef __attribute__((ext_vector_type(8))) short short8;
typedef __attribute__((ext_vector_type(4))) float f32x4;
typedef __attribute__((ext_vector_type(4))) unsigned int u32x4;
typedef __attribute__((ext_vector_type(4))) unsigned short u16x4;

typedef __attribute__((address_space(3))) unsigned int lds_uint;
typedef __attribute__((address_space(1))) unsigned int glob_uint;

__device__ __forceinline__ float asfloat(unsigned int u) { union { unsigned int i; float f; } v; v.i = u; return v.f; }
__device__ __forceinline__ unsigned int asuint(float f) { union { float f; unsigned int i; } v; v.f = f; return v.i; }
__device__ __forceinline__ unsigned short f2bf(float f) {
  unsigned int x = asuint(f);
  x += 0x7fffu + ((x >> 16) & 1u);   // round-to-nearest-even
  return (unsigned short)(x >> 16);
}
__device__ __forceinline__ float bf2f(unsigned short b) { return asfloat(((unsigned int)b) << 16); }

__device__ __forceinline__ short8 ld_b64x2(const unsigned short* p) {
  typedef __attribute__((ext_vector_type(4))) short sh4;
  sh4 lo = *(const sh4*)p;
  sh4 hi = *(const sh4*)(p + 4);
  short8 r;
  r[0] = lo[0]; r[1] = lo[1]; r[2] = lo[2]; r[3] = lo[3];
  r[4] = hi[0]; r[5] = hi[1]; r[6] = hi[2]; r[7] = hi[3];
  return r;
}

// ---------------------------------------------------------------- converts
__global__ void convert_f32_bf16(const float* __restrict__ s,
                                 unsigned short* __restrict__ d, long n4) {
  long stride = (long)gridDim.x * blockDim.x;
  for (long i = (long)blockIdx.x * blockDim.x + threadIdx.x; i < n4; i += stride) {
    f32x4 f = ((const f32x4*)s)[i];
    u16x4 o;
    o[0] = f2bf(f[0]); o[1] = f2bf(f[1]); o[2] = f2bf(f[2]); o[3] = f2bf(f[3]);
    ((u16x4*)d)[i] = o;
  }
}

// ---------------------------------------------------------------- GEMM (NT)
// C(M,N) = A(M,K) * B(N,K)^T + bias[col];  M,N multiples of 128, K multiple of 64.
// 1-D grid, N-tile fastest, T1 bijective XCD chunk swizzle (m204) so blocks
// sharing an A-panel land on one XCD's L2.
template<int OUTBF>
__global__ __launch_bounds__(256)
void gemm_nt(const unsigned short* __restrict__ A, const unsigned short* __restrict__ Bw,
             const float* __restrict__ bias, void* __restrict__ Cout,
             long M, long N, long K, int gx) {
  __shared__ unsigned short As[128 * 64];
  __shared__ unsigned short Bs[128 * 64];
  const int nwg  = gridDim.x;
  const int orig = blockIdx.x;
  const int q8 = nwg >> 3, r8 = nwg & 7;
  const int xcd = orig & 7, sub = orig >> 3;
  const int wg = (xcd < r8 ? xcd * (q8 + 1) : r8 * (q8 + 1) + (xcd - r8) * q8) + sub;
  const long nBase = (long)(wg % gx) * 128;
  const long mBase = (long)(wg / gx) * 128;

  const int tid  = threadIdx.x;
  const int lane = tid & 63;
  const int wid  = tid >> 6;
  const int wr   = wid >> 1, wc = wid & 1;
  const int r15 = lane & 15;
  const int g16 = lane >> 4;

  f32x4 acc[4][4];
#pragma unroll
  for (int a = 0; a < 4; ++a)
#pragma unroll
    for (int b = 0; b < 4; ++b) acc[a][b] = (f32x4){0.f, 0.f, 0.f, 0.f};

  const int srow = tid >> 3;        // 0..31 : row within a 32-row chunk
  const int skb  = (tid & 7) * 8;   // element offset within a row

  for (long kt = 0; kt < K; kt += 64) {
    __syncthreads();
#pragma unroll
    for (int j = 0; j < 4; ++j) {
      long row = j * 32 + srow;
      const unsigned short* ga = A  + (mBase + row) * K + kt + skb;
      const unsigned short* gb = Bw + (nBase + row) * K + kt + skb;
      __builtin_amdgcn_global_load_lds((glob_uint*)ga, (lds_uint*)(As + (j * 256 + wid * 64) * 8), 16, 0, 0);
      __builtin_amdgcn_global_load_lds((glob_uint*)gb, (lds_uint*)(Bs + (j * 256 + wid * 64) * 8), 16, 0, 0);
    }
    __syncthreads();
#pragma unroll
    for (int kk = 0; kk < 64; kk += 32) {
      short8 af[4], bfr[4];
#pragma unroll
      for (int mi = 0; mi < 4; ++mi)
        af[mi] = *(const short8*)&As[(wr * 64 + mi * 16 + r15) * 64 + kk + g16 * 8];
#pragma unroll
      for (int ni = 0; ni < 4; ++ni)
        bfr[ni] = *(const short8*)&Bs[(wc * 64 + ni * 16 + r15) * 64 + kk + g16 * 8];
#pragma unroll
      for (int mi = 0; mi < 4; ++mi)
#pragma unroll
        for (int ni = 0; ni < 4; ++ni)
          acc[mi][ni] = __builtin_amdgcn_mfma_f32_16x16x32_bf16(af[mi], bfr[ni], acc[mi][ni], 0, 0, 0);
    }
  }

  float bv[4];
  long col[4];
#pragma unroll
  for (int ni = 0; ni < 4; ++ni) { col[ni] = nBase + wc * 64 + ni * 16 + r15; bv[ni] = bias[col[ni]]; }
#pragma unroll
  for (int mi = 0; mi < 4; ++mi) {
    long row0 = mBase + wr * 64 + mi * 16 + g16 * 4;
#pragma unroll
    for (int ni = 0; ni < 4; ++ni) {
#pragma unroll
      for (int v = 0; v < 4; ++v) {
        float val = acc[mi][ni][v] + bv[ni];
        long off = (row0 + v) * N + col[ni];
        if (OUTBF) ((unsigned short*)Cout)[off] = f2bf(val);
        else       ((float*)Cout)[off] = val;
      }
    }
  }
}

// ---------------------------------------------------------------- MFMA attention
// One block per (b_, h). 4 waves. Wave w owns M-tile w (rows 16w..16w+15);
// wave 0 also owns M-tile 4 (rows 64..79, only row 64 valid).
// Q fragments come straight from global (L2-resident) — no Q in LDS.
// LDS layout (u16 elems):
//   [VT_OFF]  Vt[64][VT_STR=140]     : V^T, cols 0..128 valid       (8960)
//   [K_OFF]   K [136][64]            : rows 0..128 valid, swizzled  (8704)
//   [P_OFF=K_OFF] P[80][P_STR=136]   : overlays K after QK^T        (10880)
// total 19840 elems = 39680 B -> 4 blocks/CU.
#define VT_OFF 0
#define VT_STR 140
#define K_OFF  (64 * VT_STR)          // 8960
#define P_OFF  K_OFF
#define P_STR  136
#define SMEM_ELEMS (K_OFF + 80 * P_STR)  // 19840 elems

__global__ __launch_bounds__(256, 4)
void attn_mfma(const unsigned short* __restrict__ qb,
               const unsigned short* __restrict__ kvb,
               unsigned short* __restrict__ aob,
               const float* __restrict__ rel_table,
               const float* __restrict__ cls_self,
               const float* __restrict__ cls_up,
               const float* __restrict__ cls_down,
               const int* __restrict__ mask_left,
               const int* __restrict__ mask_right,
               const int* __restrict__ nWp, int mcL) {
  __shared__ unsigned short smem[SMEM_ELEMS];
  const int h   = blockIdx.x;
  const int b_  = blockIdx.y;
  const int tid = threadIdx.x, lane = tid & 63, wid = tid >> 6;
  const int r15 = lane & 15, g16 = lane >> 4;

  const int nW = nWp[0];
  const int w  = b_ % nW;
  const int mc = min(mcL, nW);
  const bool useL = (w < mc);
  const bool useR = (w >= nW - mc);
  const int wR = mcL - mc + (w - (nW - mc));

  const unsigned short* kgbase = kvb + (long)b_ * MSEQ * (2 * DIMC) + h * HDIM;       // K, row stride 1024
  const unsigned short* vgbase = kgbase + DIMC;                                       // V
  const unsigned short* qgbase = qb  + (long)b_ * NSEQ * DIMC + h * HDIM;             // Q, row stride 512

  // ---- K staging via global_load_lds. Source col pre-swizzled (rule #21):
  // LDS[row][col16 ^ (row&7)] = global[row][col16]; reads XOR-unswizzle.
  const int lr  = lane >> 3;                                  // row within 8-row chunk
  const int lcs = ((lane & 7) ^ (lr & 7)) * 8;                // swizzled source col (elems)
#pragma unroll
  for (int j = 0; j < 4; ++j) {
    int chunk = j * 4 + wid;                                  // 0..15 -> rows 0..127
    int gr = chunk * 8 + lr;
    __builtin_amdgcn_global_load_lds((glob_uint*)(kgbase + (long)gr * (2 * DIMC) + lcs),
                                     (lds_uint*)(smem + K_OFF + chunk * 512), 16, 0, 0);
  }
  if (wid == 0) {                                             // chunk 16: rows 128..135 (dup 128)
    __builtin_amdgcn_global_load_lds((glob_uint*)(kgbase + (long)128 * (2 * DIMC) + lcs),
                                     (lds_uint*)(smem + K_OFF + 16 * 512), 16, 0, 0);
  }
  __syncthreads();   // K ready (only K-DMA outstanding here)

  // ---- issue V global->reg loads (latency hides under QK^T)
  u32x4 vreg[5];
#pragma unroll
  for (int it = 0; it < 5; ++it) {
    int idx = it * 256 + tid;
    if (idx < MSEQ * 8) {
      int c = idx >> 3, d0 = (idx & 7) * 8;
      vreg[it] = *(const u32x4*)(vgbase + (long)c * (2 * DIMC) + d0);
    }
  }

  // ---- phase A: QK^T, S in registers. S[t][ni][v]: row=i0+g16*4+v, col=16ni+r15.
  f32x4 S[2][9];
  const int swz = (r15 & 7) << 3;
#pragma unroll
  for (int t = 0; t < 2; ++t) {
    if (t == 1 && wid != 0) continue;
    const int i0 = (t == 0 ? wid : 4) * 16;
    const int qrow = min(i0 + r15, NSEQ - 1);
    const unsigned short* qp = qgbase + (long)qrow * DIMC;
    short8 a0 = *(const short8*)(qp + g16 * 8);
    short8 a1 = *(const short8*)(qp + 32 + g16 * 8);
#pragma unroll
    for (int ni = 0; ni < 9; ++ni) {
      short8 b0 = *(const short8*)&smem[K_OFF + (ni * 16 + r15) * 64 + ((g16 * 8) ^ swz)];
      short8 b1 = *(const short8*)&smem[K_OFF + (ni * 16 + r15) * 64 + ((32 + g16 * 8) ^ swz)];
      f32x4 c = (f32x4){0.f, 0.f, 0.f, 0.f};
      c = __builtin_amdgcn_mfma_f32_16x16x32_bf16(a0, b0, c, 0, 0, 0);
      c = __builtin_amdgcn_mfma_f32_16x16x32_bf16(a1, b1, c, 0, 0, 0);
      S[t][ni] = c;
    }
  }

  // ---- Vt transpose writes (Vt region untouched by QK^T; overlaps softmax)
#pragma unroll
  for (int it = 0; it < 5; ++it) {
    int idx = it * 256 + tid;
    if (idx < MSEQ * 8) {
      int c = idx >> 3, d0 = (idx & 7) * 8;
      u32x4 u = vreg[it];
#pragma unroll
      for (int jj = 0; jj < 4; ++jj) {
        smem[VT_OFF + (d0 + 2 * jj) * VT_STR + c]     = (unsigned short)(u[jj] & 0xffffu);
        smem[VT_OFF + (d0 + 2 * jj + 1) * VT_STR + c] = (unsigned short)(u[jj] >> 16);
      }
    }
  }

  // ---- phase B (registers): scale + bias + mask + softmax
  float p128[2][4];
#pragma unroll
  for (int t = 0; t < 2; ++t) {
    if (t == 1 && wid != 0) continue;
    const int i0 = (t == 0 ? wid : 4) * 16;
#pragma unroll
    for (int v = 0; v < 4; ++v) {
      int row  = i0 + g16 * 4 + v;
      int rowb = min(row, NSEQ - 1);
#pragma unroll
      for (int ni = 0; ni < 9; ++ni) {
        int col = ni * 16 + r15;
        float val;
        if (col > 128) {
          val = -FLT_MAX;
        } else {
          float bias;
          if (row == 0) bias = (col == 0) ? cls_self[h] : cls_up[h * RR + col - 1];
          else bias = (col == 0) ? cls_down[h * WW + rowb - 1]
                                 : rel_table[min(rowb - col + 127, 190) * NH + h];
          val = S[t][ni][v] * 0.125f + bias;
          if (useL && mask_left[((long)w * NSEQ + rowb) * MSEQ + col])  val = -FLT_MAX;
          if (useR && mask_right[((long)wR * NSEQ + rowb) * MSEQ + col]) val = -FLT_MAX;
        }
        S[t][ni][v] = val;
      }
    }
#pragma unroll
    for (int v = 0; v < 4; ++v) {
      float m = S[t][0][v];
#pragma unroll
      for (int ni = 1; ni < 9; ++ni) m = fmaxf(m, S[t][ni][v]);
#pragma unroll
      for (int off = 1; off < 16; off <<= 1) m = fmaxf(m, __shfl_xor(m, off, 64));
      float sum = 0.f;
#pragma unroll
      for (int ni = 0; ni < 9; ++ni) {
        float p = __expf(S[t][ni][v] - m);
        S[t][ni][v] = p;
        sum += p;
      }
#pragma unroll
      for (int off = 1; off < 16; off <<= 1) sum += __shfl_xor(sum, off, 64);
      float inv = 1.0f / sum;
#pragma unroll
      for (int ni = 0; ni < 9; ++ni) S[t][ni][v] *= inv;
    }
#pragma unroll
    for (int v = 0; v < 4; ++v) p128[t][v] = S[t][8][v];   // valid in lanes r15==0
  }
  __syncthreads();   // all K reads done before P overwrites that region

  // ---- P writes (bf16, overlays K region)
#pragma unroll
  for (int t = 0; t < 2; ++t) {
    if (t == 1 && wid != 0) continue;
    const int i0 = (t == 0 ? wid : 4) * 16;
#pragma unroll
    for (int ni = 0; ni < 8; ++ni)
#pragma unroll
      for (int v = 0; v < 4; ++v)
        smem[P_OFF + (i0 + g16 * 4 + v) * P_STR + ni * 16 + r15] = f2bf(S[t][ni][v]);
  }
  __syncthreads();   // P + Vt visible to all

  // ---- phase C: PV MFMAs (k = 0..127) + rank-1 col-128 + store.
#pragma unroll
  for (int t = 0; t < 2; ++t) {
    if (t == 1 && wid != 0) continue;
    const int i0 = (t == 0 ? wid : 4) * 16;
    short8 pa[4];
#pragma unroll
    for (int kk = 0; kk < 4; ++kk)
      pa[kk] = *(const short8*)&smem[P_OFF + (i0 + r15) * P_STR + kk * 32 + g16 * 8];
    f32x4 acc[4];
#pragma unroll
    for (int nt = 0; nt < 4; ++nt) acc[nt] = (f32x4){0.f, 0.f, 0.f, 0.f};
#pragma unroll
    for (int nt = 0; nt < 4; ++nt)
#pragma unroll
      for (int kk = 0; kk < 4; ++kk) {
        short8 bv = ld_b64x2(&smem[VT_OFF + (nt * 16 + r15) * VT_STR + kk * 32 + g16 * 8]);
        acc[nt] = __builtin_amdgcn_mfma_f32_16x16x32_bf16(pa[kk], bv, acc[nt], 0, 0, 0);
      }
    float p1b[4];
#pragma unroll
    for (int v = 0; v < 4; ++v) p1b[v] = __shfl(p128[t][v], (lane & 48), 64);
#pragma unroll
    for (int nt = 0; nt < 4; ++nt) {
      float v128 = bf2f(smem[VT_OFF + (nt * 16 + r15) * VT_STR + 128]);
#pragma unroll
      for (int v = 0; v < 4; ++v) {
        int row = i0 + g16 * 4 + v;
        if (row < NSEQ) {
          float o = acc[nt][v] + p1b[v] * v128;
          aob[((long)b_ * NSEQ + row) * DIMC + h * HDIM + nt * 16 + r15] = f2bf(o);
        }
      }
    }
  }
}

// ---------------------------------------------------------------- launch
extern "C" void kernel_launch(void* const* d_in, const int* in_sizes, int n_in,
                              void* d_out, int out_size, void* d_ws, size_t ws_size,
                              hipStream_t stream) {
  const float* x          = (const float*)d_in[0];
  const float* x_         = (const float*)d_in[1];
  const int*   mask_left  = (const int*)d_in[2];
  const int*   mask_right = (const int*)d_in[3];
  const int*   nWp        = (const int*)d_in[4];
  const float* rel_table  = (const float*)d_in[5];
  const float* cls_self   = (const float*)d_in[6];
  const float* cls_up     = (const float*)d_in[7];
  const float* cls_down   = (const float*)d_in[8];
  const float* Wq         = (const float*)d_in[9];
  const float* bq         = (const float*)d_in[10];
  const float* Wkv        = (const float*)d_in[11];
  const float* bkv        = (const float*)d_in[12];
  const float* Wp         = (const float*)d_in[13];
  const float* bp         = (const float*)d_in[14];

  const long B_  = in_sizes[0] / (NSEQ * DIMC);          // 512
  const int  mcL = in_sizes[2] / (NSEQ * MSEQ);          // 4
  const long Mq  = B_ * NSEQ;                            // 33280
  const long Mkv = B_ * MSEQ;                            // 66048

  // workspace layout (bf16 elements)
  unsigned short* xb    = (unsigned short*)d_ws;
  unsigned short* x_b   = xb    + Mq  * DIMC;
  unsigned short* wqb   = x_b   + Mkv * DIMC;
  unsigned short* wkvb  = wqb   + DIMC * DIMC;
  unsigned short* wpb   = wkvb  + 2 * DIMC * DIMC;
  unsigned short* qbuf  = wpb   + DIMC * DIMC;
  unsigned short* kvbuf = qbuf  + Mq  * DIMC;
  unsigned short* aob   = kvbuf + Mkv * 2 * DIMC;
  const size_t needed = (size_t)(Mq * DIMC * 3 + Mkv * DIMC * 3 + 4 * DIMC * DIMC) * 2;
  if (ws_size < needed) return;

  auto cv = [&](const float* s, unsigned short* d, long n) {
    long n4 = n / 4;
    int blocks = (int)((n4 + 255) / 256); if (blocks > 8192) blocks = 8192;
    convert_f32_bf16<<<blocks, 256, 0, stream>>>(s, d, n4);
  };
  cv(x,   xb,   Mq * DIMC);
  cv(x_,  x_b,  Mkv * DIMC);
  cv(Wq,  wqb,  (long)DIMC * DIMC);
  cv(Wkv, wkvb, 2L * DIMC * DIMC);
  cv(Wp,  wpb,  (long)DIMC * DIMC);

  {
    int gx = DIMC / 128, nwg = (int)(gx * (Mq / 128));
    gemm_nt<1><<<nwg, 256, 0, stream>>>(xb, wqb, bq, qbuf, Mq, DIMC, DIMC, gx);
  }
  {
    int gx = 2 * DIMC / 128, nwg = (int)(gx * (Mkv / 128));
    gemm_nt<1><<<nwg, 256, 0, stream>>>(x_b, wkvb, bkv, kvbuf, Mkv, 2 * DIMC, DIMC, gx);
  }

  attn_mfma<<<dim3(NH, (unsigned)B_), 256, 0, stream>>>(
      qbuf, kvbuf, aob, rel_table, cls_self, cls_up, cls_down,
      mask_left, mask_right, nWp, mcL);

  {
    int gx = DIMC / 128, nwg = (int)(gx * (Mq / 128));
    gemm_nt<0><<<nwg, 256, 0, stream>>>(aob, wpb, bp, d_out, Mq, DIMC, DIMC, gx);
  }
}

// Round 5
// 653.228 us; speedup vs baseline: 1.1041x; 1.1041x over previous
//
#include <hip/hip_runtime.h>
#include <float.h>

#define DIMC 512
#define WW 64
#define RR 128
#define NH 8
#define HDIM 64
#define NSEQ 65      // 1+W
#define MSEQ 129     // 1+R

typedef __attribute__((ext_vector_type(8))) short short8;
typedef __attribute__((ext_vector_type(4))) float f32x4;
typedef __attribute__((ext_vector_type(4))) unsigned int u32x4;
typedef __attribute__((ext_vector_type(4))) unsigned short u16x4;

typedef __attribute__((address_space(3))) unsigned int lds_uint;
typedef __attribute__((address_space(1))) unsigned int glob_uint;

__device__ __forceinline__ float asfloat(unsigned int u) { union { unsigned int i; float f; } v; v.i = u; return v.f; }
__device__ __forceinline__ unsigned int asuint(float f) { union { float f; unsigned int i; } v; v.f = f; return v.i; }
__device__ __forceinline__ unsigned short f2bf(float f) {
  unsigned int x = asuint(f);
  x += 0x7fffu + ((x >> 16) & 1u);   // round-to-nearest-even
  return (unsigned short)(x >> 16);
}
__device__ __forceinline__ float bf2f(unsigned short b) { return asfloat(((unsigned int)b) << 16); }

__device__ __forceinline__ short8 ld_b64x2(const unsigned short* p) {
  typedef __attribute__((ext_vector_type(4))) short sh4;
  sh4 lo = *(const sh4*)p;
  sh4 hi = *(const sh4*)(p + 4);
  short8 r;
  r[0] = lo[0]; r[1] = lo[1]; r[2] = lo[2]; r[3] = lo[3];
  r[4] = hi[0]; r[5] = hi[1]; r[6] = hi[2]; r[7] = hi[3];
  return r;
}

// ---------------------------------------------------------------- converts
__global__ void convert_f32_bf16(const float* __restrict__ s,
                                 unsigned short* __restrict__ d, long n4) {
  long stride = (long)gridDim.x * blockDim.x;
  for (long i = (long)blockIdx.x * blockDim.x + threadIdx.x; i < n4; i += stride) {
    f32x4 f = ((const f32x4*)s)[i];
    u16x4 o;
    o[0] = f2bf(f[0]); o[1] = f2bf(f[1]); o[2] = f2bf(f[2]); o[3] = f2bf(f[3]);
    ((u16x4*)d)[i] = o;
  }
}

// ---------------------------------------------------------------- GEMM (NT)
// C(M,N) = A(M,K) * B(N,K)^T + bias[col];  M,N multiples of 128, K multiple of 64.
// 1-D grid, N-tile fastest, T1 bijective XCD chunk swizzle (m204).
template<int OUTBF>
__global__ __launch_bounds__(256)
void gemm_nt(const unsigned short* __restrict__ A, const unsigned short* __restrict__ Bw,
             const float* __restrict__ bias, void* __restrict__ Cout,
             long M, long N, long K, int gx) {
  __shared__ unsigned short As[128 * 64];
  __shared__ unsigned short Bs[128 * 64];
  const int nwg  = gridDim.x;
  const int orig = blockIdx.x;
  const int q8 = nwg >> 3, r8 = nwg & 7;
  const int xcd = orig & 7, sub = orig >> 3;
  const int wg = (xcd < r8 ? xcd * (q8 + 1) : r8 * (q8 + 1) + (xcd - r8) * q8) + sub;
  const long nBase = (long)(wg % gx) * 128;
  const long mBase = (long)(wg / gx) * 128;

  const int tid  = threadIdx.x;
  const int lane = tid & 63;
  const int wid  = tid >> 6;
  const int wr   = wid >> 1, wc = wid & 1;
  const int r15 = lane & 15;
  const int g16 = lane >> 4;

  f32x4 acc[4][4];
#pragma unroll
  for (int a = 0; a < 4; ++a)
#pragma unroll
    for (int b = 0; b < 4; ++b) acc[a][b] = (f32x4){0.f, 0.f, 0.f, 0.f};

  const int srow = tid >> 3;        // 0..31 : row within a 32-row chunk
  const int skb  = (tid & 7) * 8;   // element offset within a row

  for (long kt = 0; kt < K; kt += 64) {
    __syncthreads();
#pragma unroll
    for (int j = 0; j < 4; ++j) {
      long row = j * 32 + srow;
      const unsigned short* ga = A  + (mBase + row) * K + kt + skb;
      const unsigned short* gb = Bw + (nBase + row) * K + kt + skb;
      __builtin_amdgcn_global_load_lds((glob_uint*)ga, (lds_uint*)(As + (j * 256 + wid * 64) * 8), 16, 0, 0);
      __builtin_amdgcn_global_load_lds((glob_uint*)gb, (lds_uint*)(Bs + (j * 256 + wid * 64) * 8), 16, 0, 0);
    }
    __syncthreads();
#pragma unroll
    for (int kk = 0; kk < 64; kk += 32) {
      short8 af[4], bfr[4];
#pragma unroll
      for (int mi = 0; mi < 4; ++mi)
        af[mi] = *(const short8*)&As[(wr * 64 + mi * 16 + r15) * 64 + kk + g16 * 8];
#pragma unroll
      for (int ni = 0; ni < 4; ++ni)
        bfr[ni] = *(const short8*)&Bs[(wc * 64 + ni * 16 + r15) * 64 + kk + g16 * 8];
#pragma unroll
      for (int mi = 0; mi < 4; ++mi)
#pragma unroll
        for (int ni = 0; ni < 4; ++ni)
          acc[mi][ni] = __builtin_amdgcn_mfma_f32_16x16x32_bf16(af[mi], bfr[ni], acc[mi][ni], 0, 0, 0);
    }
  }

  float bv[4];
  long col[4];
#pragma unroll
  for (int ni = 0; ni < 4; ++ni) { col[ni] = nBase + wc * 64 + ni * 16 + r15; bv[ni] = bias[col[ni]]; }
#pragma unroll
  for (int mi = 0; mi < 4; ++mi) {
    long row0 = mBase + wr * 64 + mi * 16 + g16 * 4;
#pragma unroll
    for (int ni = 0; ni < 4; ++ni) {
#pragma unroll
      for (int v = 0; v < 4; ++v) {
        float val = acc[mi][ni][v] + bv[ni];
        long off = (row0 + v) * N + col[ni];
        if (OUTBF) ((unsigned short*)Cout)[off] = f2bf(val);
        else       ((float*)Cout)[off] = val;
      }
    }
  }
}

// ---------------------------------------------------------------- MFMA attention
// One block per (b_, h). 4 waves. Wave w owns M-tile w (rows 16w..16w+15);
// wave 0 also owns M-tile 4 (rows 64..79, only row 64 valid).
// Q fragments come straight from global (L2-resident) — no Q in LDS.
// V staged directly global->LDS-transposed at kernel start (transient regs
// only — round-4's persistent vreg[] buffer caused a VGPR spill, WRITE_SIZE
// 33->243 MB; launch_bounds back to (256,3), the proven-no-spill setting.
// LDS (u16 elems): Vt[64][140] (8960) ; K 17x512 at K_OFF, P[80][136] overlays.
// total 19840 elems = 39680 B -> 4 blocks/CU (LDS-limited).
#define VT_OFF 0
#define VT_STR 140
#define K_OFF  (64 * VT_STR)          // 8960
#define P_OFF  K_OFF
#define P_STR  136
#define SMEM_ELEMS (K_OFF + 80 * P_STR)  // 19840 elems

__global__ __launch_bounds__(256, 3)
void attn_mfma(const unsigned short* __restrict__ qb,
               const unsigned short* __restrict__ kvb,
               unsigned short* __restrict__ aob,
               const float* __restrict__ rel_table,
               const float* __restrict__ cls_self,
               const float* __restrict__ cls_up,
               const float* __restrict__ cls_down,
               const int* __restrict__ mask_left,
               const int* __restrict__ mask_right,
               const int* __restrict__ nWp, int mcL) {
  __shared__ unsigned short smem[SMEM_ELEMS];
  const int h   = blockIdx.x;
  const int b_  = blockIdx.y;
  const int tid = threadIdx.x, lane = tid & 63, wid = tid >> 6;
  const int r15 = lane & 15, g16 = lane >> 4;

  const int nW = nWp[0];
  const int w  = b_ % nW;
  const int mc = min(mcL, nW);
  const bool useL = (w < mc);
  const bool useR = (w >= nW - mc);
  const int wR = mcL - mc + (w - (nW - mc));

  const unsigned short* kgbase = kvb + (long)b_ * MSEQ * (2 * DIMC) + h * HDIM;       // K, row stride 1024
  const unsigned short* vgbase = kgbase + DIMC;                                       // V
  const unsigned short* qgbase = qb  + (long)b_ * NSEQ * DIMC + h * HDIM;             // Q, row stride 512

  // ---- K staging via global_load_lds. Source col pre-swizzled (rule #21):
  // LDS[row][col16 ^ (row&7)] = global[row][col16]; reads XOR-unswizzle.
  const int lr  = lane >> 3;                                  // row within 8-row chunk
  const int lcs = ((lane & 7) ^ (lr & 7)) * 8;                // swizzled source col (elems)
#pragma unroll
  for (int j = 0; j < 4; ++j) {
    int chunk = j * 4 + wid;                                  // 0..15 -> rows 0..127
    int gr = chunk * 8 + lr;
    __builtin_amdgcn_global_load_lds((glob_uint*)(kgbase + (long)gr * (2 * DIMC) + lcs),
                                     (lds_uint*)(smem + K_OFF + chunk * 512), 16, 0, 0);
  }
  if (wid == 0) {                                             // chunk 16: rows 128..135 (dup 128)
    __builtin_amdgcn_global_load_lds((glob_uint*)(kgbase + (long)128 * (2 * DIMC) + lcs),
                                     (lds_uint*)(smem + K_OFF + 16 * 512), 16, 0, 0);
  }

  // ---- V transpose staging, direct global->LDS (transient regs only).
  // Vt region is disjoint from the in-flight K DMA region.
  for (int it = 0; it < 5; ++it) {
    int idx = it * 256 + tid;
    if (idx < MSEQ * 8) {
      int c = idx >> 3, d0 = (idx & 7) * 8;
      u32x4 u = *(const u32x4*)(vgbase + (long)c * (2 * DIMC) + d0);
#pragma unroll
      for (int jj = 0; jj < 4; ++jj) {
        smem[VT_OFF + (d0 + 2 * jj) * VT_STR + c]     = (unsigned short)(u[jj] & 0xffffu);
        smem[VT_OFF + (d0 + 2 * jj + 1) * VT_STR + c] = (unsigned short)(u[jj] >> 16);
      }
    }
  }
  __syncthreads();   // K DMA + Vt writes complete

  // ---- phase A: QK^T, S in registers. S[t][ni][v]: row=i0+g16*4+v, col=16ni+r15.
  f32x4 S[2][9];
  const int swz = (r15 & 7) << 3;
#pragma unroll
  for (int t = 0; t < 2; ++t) {
    if (t == 1 && wid != 0) continue;
    const int i0 = (t == 0 ? wid : 4) * 16;
    const int qrow = min(i0 + r15, NSEQ - 1);
    const unsigned short* qp = qgbase + (long)qrow * DIMC;
    short8 a0 = *(const short8*)(qp + g16 * 8);
    short8 a1 = *(const short8*)(qp + 32 + g16 * 8);
#pragma unroll
    for (int ni = 0; ni < 9; ++ni) {
      short8 b0 = *(const short8*)&smem[K_OFF + (ni * 16 + r15) * 64 + ((g16 * 8) ^ swz)];
      short8 b1 = *(const short8*)&smem[K_OFF + (ni * 16 + r15) * 64 + ((32 + g16 * 8) ^ swz)];
      f32x4 c = (f32x4){0.f, 0.f, 0.f, 0.f};
      c = __builtin_amdgcn_mfma_f32_16x16x32_bf16(a0, b0, c, 0, 0, 0);
      c = __builtin_amdgcn_mfma_f32_16x16x32_bf16(a1, b1, c, 0, 0, 0);
      S[t][ni] = c;
    }
  }

  // ---- phase B (registers): scale + bias + mask + softmax
  float p128[2][4];
#pragma unroll
  for (int t = 0; t < 2; ++t) {
    if (t == 1 && wid != 0) continue;
    const int i0 = (t == 0 ? wid : 4) * 16;
#pragma unroll
    for (int v = 0; v < 4; ++v) {
      int row  = i0 + g16 * 4 + v;
      int rowb = min(row, NSEQ - 1);
#pragma unroll
      for (int ni = 0; ni < 9; ++ni) {
        int col = ni * 16 + r15;
        float val;
        if (col > 128) {
          val = -FLT_MAX;
        } else {
          float bias;
          if (row == 0) bias = (col == 0) ? cls_self[h] : cls_up[h * RR + col - 1];
          else bias = (col == 0) ? cls_down[h * WW + rowb - 1]
                                 : rel_table[min(rowb - col + 127, 190) * NH + h];
          val = S[t][ni][v] * 0.125f + bias;
          if (useL && mask_left[((long)w * NSEQ + rowb) * MSEQ + col])  val = -FLT_MAX;
          if (useR && mask_right[((long)wR * NSEQ + rowb) * MSEQ + col]) val = -FLT_MAX;
        }
        S[t][ni][v] = val;
      }
    }
#pragma unroll
    for (int v = 0; v < 4; ++v) {
      float m = S[t][0][v];
#pragma unroll
      for (int ni = 1; ni < 9; ++ni) m = fmaxf(m, S[t][ni][v]);
#pragma unroll
      for (int off = 1; off < 16; off <<= 1) m = fmaxf(m, __shfl_xor(m, off, 64));
      float sum = 0.f;
#pragma unroll
      for (int ni = 0; ni < 9; ++ni) {
        float p = __expf(S[t][ni][v] - m);
        S[t][ni][v] = p;
        sum += p;
      }
#pragma unroll
      for (int off = 1; off < 16; off <<= 1) sum += __shfl_xor(sum, off, 64);
      float inv = 1.0f / sum;
#pragma unroll
      for (int ni = 0; ni < 9; ++ni) S[t][ni][v] *= inv;
    }
#pragma unroll
    for (int v = 0; v < 4; ++v) p128[t][v] = S[t][8][v];   // valid in lanes r15==0
  }
  __syncthreads();   // all K reads done before P overwrites that region

  // ---- P writes (bf16, overlays K region)
#pragma unroll
  for (int t = 0; t < 2; ++t) {
    if (t == 1 && wid != 0) continue;
    const int i0 = (t == 0 ? wid : 4) * 16;
#pragma unroll
    for (int ni = 0; ni < 8; ++ni)
#pragma unroll
      for (int v = 0; v < 4; ++v)
        smem[P_OFF + (i0 + g16 * 4 + v) * P_STR + ni * 16 + r15] = f2bf(S[t][ni][v]);
  }
  __syncthreads();   // P visible to all

  // ---- phase C: PV MFMAs (k = 0..127) + rank-1 col-128 + store.
#pragma unroll
  for (int t = 0; t < 2; ++t) {
    if (t == 1 && wid != 0) continue;
    const int i0 = (t == 0 ? wid : 4) * 16;
    short8 pa[4];
#pragma unroll
    for (int kk = 0; kk < 4; ++kk)
      pa[kk] = *(const short8*)&smem[P_OFF + (i0 + r15) * P_STR + kk * 32 + g16 * 8];
    f32x4 acc[4];
#pragma unroll
    for (int nt = 0; nt < 4; ++nt) acc[nt] = (f32x4){0.f, 0.f, 0.f, 0.f};
#pragma unroll
    for (int nt = 0; nt < 4; ++nt)
#pragma unroll
      for (int kk = 0; kk < 4; ++kk) {
        short8 bv = ld_b64x2(&smem[VT_OFF + (nt * 16 + r15) * VT_STR + kk * 32 + g16 * 8]);
        acc[nt] = __builtin_amdgcn_mfma_f32_16x16x32_bf16(pa[kk], bv, acc[nt], 0, 0, 0);
      }
    float p1b[4];
#pragma unroll
    for (int v = 0; v < 4; ++v) p1b[v] = __shfl(p128[t][v], (lane & 48), 64);
#pragma unroll
    for (int nt = 0; nt < 4; ++nt) {
      float v128 = bf2f(smem[VT_OFF + (nt * 16 + r15) * VT_STR + 128]);
#pragma unroll
      for (int v = 0; v < 4; ++v) {
        int row = i0 + g16 * 4 + v;
        if (row < NSEQ) {
          float o = acc[nt][v] + p1b[v] * v128;
          aob[((long)b_ * NSEQ + row) * DIMC + h * HDIM + nt * 16 + r15] = f2bf(o);
        }
      }
    }
  }
}

// ---------------------------------------------------------------- launch
extern "C" void kernel_launch(void* const* d_in, const int* in_sizes, int n_in,
                              void* d_out, int out_size, void* d_ws, size_t ws_size,
                              hipStream_t stream) {
  const float* x          = (const float*)d_in[0];
  const float* x_         = (const float*)d_in[1];
  const int*   mask_left  = (const int*)d_in[2];
  const int*   mask_right = (const int*)d_in[3];
  const int*   nWp        = (const int*)d_in[4];
  const float* rel_table  = (const float*)d_in[5];
  const float* cls_self   = (const float*)d_in[6];
  const float* cls_up     = (const float*)d_in[7];
  const float* cls_down   = (const float*)d_in[8];
  const float* Wq         = (const float*)d_in[9];
  const float* bq         = (const float*)d_in[10];
  const float* Wkv        = (const float*)d_in[11];
  const float* bkv        = (const float*)d_in[12];
  const float* Wp         = (const float*)d_in[13];
  const float* bp         = (const float*)d_in[14];

  const long B_  = in_sizes[0] / (NSEQ * DIMC);          // 512
  const int  mcL = in_sizes[2] / (NSEQ * MSEQ);          // 4
  const long Mq  = B_ * NSEQ;                            // 33280
  const long Mkv = B_ * MSEQ;                            // 66048

  // workspace layout (bf16 elements)
  unsigned short* xb    = (unsigned short*)d_ws;
  unsigned short* x_b   = xb    + Mq  * DIMC;
  unsigned short* wqb   = x_b   + Mkv * DIMC;
  unsigned short* wkvb  = wqb   + DIMC * DIMC;
  unsigned short* wpb   = wkvb  + 2 * DIMC * DIMC;
  unsigned short* qbuf  = wpb   + DIMC * DIMC;
  unsigned short* kvbuf = qbuf  + Mq  * DIMC;
  unsigned short* aob   = kvbuf + Mkv * 2 * DIMC;
  const size_t needed = (size_t)(Mq * DIMC * 3 + Mkv * DIMC * 3 + 4 * DIMC * DIMC) * 2;
  if (ws_size < needed) return;

  auto cv = [&](const float* s, unsigned short* d, long n) {
    long n4 = n / 4;
    int blocks = (int)((n4 + 255) / 256); if (blocks > 8192) blocks = 8192;
    convert_f32_bf16<<<blocks, 256, 0, stream>>>(s, d, n4);
  };
  cv(x,   xb,   Mq * DIMC);
  cv(x_,  x_b,  Mkv * DIMC);
  cv(Wq,  wqb,  (long)DIMC * DIMC);
  cv(Wkv, wkvb, 2L * DIMC * DIMC);
  cv(Wp,  wpb,  (long)DIMC * DIMC);

  {
    int gx = DIMC / 128, nwg = (int)(gx * (Mq / 128));
    gemm_nt<1><<<nwg, 256, 0, stream>>>(xb, wqb, bq, qbuf, Mq, DIMC, DIMC, gx);
  }
  {
    int gx = 2 * DIMC / 128, nwg = (int)(gx * (Mkv / 128));
    gemm_nt<1><<<nwg, 256, 0, stream>>>(x_b, wkvb, bkv, kvbuf, Mkv, 2 * DIMC, DIMC, gx);
  }

  attn_mfma<<<dim3(NH, (unsigned)B_), 256, 0, stream>>>(
      qbuf, kvbuf, aob, rel_table, cls_self, cls_up, cls_down,
      mask_left, mask_right, nWp, mcL);

  {
    int gx = DIMC / 128, nwg = (int)(gx * (Mq / 128));
    gemm_nt<0><<<nwg, 256, 0, stream>>>(aob, wpb, bp, d_out, Mq, DIMC, DIMC, gx);
  }
}